// Round 4
// baseline (355.724 us; speedup 1.0000x reference)
//
#include <hip/hip_runtime.h>
#include <hip/hip_bf16.h>

#define BB 16
#define EE 128
#define MM 64
#define DQ 768
#define DK 256
#define NA 4   // attention tiles (consecutive a) pipelined per block

typedef __attribute__((ext_vector_type(8))) short short8v;   // 8 bf16 = 4 VGPR
typedef __attribute__((ext_vector_type(4))) float f32x4;

#define MFMA16(a, b, c) __builtin_amdgcn_mfma_f32_16x16x32_bf16(a, b, c, 0, 0, 0)

__device__ __forceinline__ ushort f2bf(float f) {
  __hip_bfloat16 h = __float2bfloat16(f);
  return *reinterpret_cast<ushort*>(&h);
}
__device__ __forceinline__ uint pack2(float lo, float hi) {
  return (uint)f2bf(lo) | ((uint)f2bf(hi) << 16);
}

// ---------------------------------------------------------------------------
// K1: WfT[e][d] = sum_k Wq[d][k] * Wk[e][k]  (= (Wq @ Wk^T)^T, bf16) via MFMA.
// A = Wk rows (e), B = Wq rows (d)  ->  C[row=e][col=d]; stores d-contiguous.
// Grid (256/16, 768/64) = (16,12), 64 threads (1 wave), 32 MFMA/block.
// ---------------------------------------------------------------------------
__global__ __launch_bounds__(64) void k_wfuse(const float* __restrict__ Wq,
                                              const float* __restrict__ Wk,
                                              ushort* __restrict__ wfT) {
  const int lane = threadIdx.x & 63;
  const int lo = lane & 15, hi = lane >> 4;
  const int e0 = blockIdx.x * 16;
  const int d0 = blockIdx.y * 64;
  f32x4 acc[4] = {f32x4{0.f, 0.f, 0.f, 0.f}, f32x4{0.f, 0.f, 0.f, 0.f},
                  f32x4{0.f, 0.f, 0.f, 0.f}, f32x4{0.f, 0.f, 0.f, 0.f}};
#pragma unroll
  for (int ks = 0; ks < 8; ++ks) {
    const int k = ks * 32 + 8 * hi;
    const float4 a0 = *(const float4*)&Wk[(size_t)(e0 + lo) * DK + k];
    const float4 a1 = *(const float4*)&Wk[(size_t)(e0 + lo) * DK + k + 4];
    union { short8v v; uint u[4]; } av;
    av.u[0] = pack2(a0.x, a0.y); av.u[1] = pack2(a0.z, a0.w);
    av.u[2] = pack2(a1.x, a1.y); av.u[3] = pack2(a1.z, a1.w);
#pragma unroll
    for (int dt = 0; dt < 4; ++dt) {
      const float4 b0 = *(const float4*)&Wq[(size_t)(d0 + dt * 16 + lo) * DK + k];
      const float4 b1 = *(const float4*)&Wq[(size_t)(d0 + dt * 16 + lo) * DK + k + 4];
      union { short8v v; uint u[4]; } bv;
      bv.u[0] = pack2(b0.x, b0.y); bv.u[1] = pack2(b0.z, b0.w);
      bv.u[2] = pack2(b1.x, b1.y); bv.u[3] = pack2(b1.z, b1.w);
      acc[dt] = MFMA16(av.v, bv.v, acc[dt]);
    }
  }
#pragma unroll
  for (int dt = 0; dt < 4; ++dt)
#pragma unroll
    for (int r = 0; r < 4; ++r)
      wfT[(size_t)(e0 + 4 * hi + r) * DQ + d0 + dt * 16 + lo] = f2bf(acc[dt][r]);
}

// ---------------------------------------------------------------------------
// K2: qt[r][e] = sum_d relu(querys[r][d]) * WfT[e][d], bf16 MFMA, no LDS.
// ---------------------------------------------------------------------------
__global__ __launch_bounds__(128) void k_qt(const float* __restrict__ querys,
                                            const ushort* __restrict__ wfT,
                                            ushort* __restrict__ qt) {
  const int tid = threadIdx.x;
  const int w = tid >> 6;
  const int lane = tid & 63;
  const int lo = lane & 15, hi = lane >> 4;
  const int r0 = blockIdx.x * 32 + w * 16;
  const int e0 = blockIdx.y * 64;
  const float* qrow = querys + (size_t)(r0 + lo) * DQ;
  f32x4 acc[4] = {f32x4{0.f, 0.f, 0.f, 0.f}, f32x4{0.f, 0.f, 0.f, 0.f},
                  f32x4{0.f, 0.f, 0.f, 0.f}, f32x4{0.f, 0.f, 0.f, 0.f}};
#pragma unroll
  for (int kc = 0; kc < DQ; kc += 32) {
    const int k = kc + 8 * hi;
    const float4 a0 = *(const float4*)&qrow[k];
    const float4 a1 = *(const float4*)&qrow[k + 4];
    union { short8v v; uint u[4]; } af;
    af.u[0] = pack2(fmaxf(a0.x, 0.f), fmaxf(a0.y, 0.f));
    af.u[1] = pack2(fmaxf(a0.z, 0.f), fmaxf(a0.w, 0.f));
    af.u[2] = pack2(fmaxf(a1.x, 0.f), fmaxf(a1.y, 0.f));
    af.u[3] = pack2(fmaxf(a1.z, 0.f), fmaxf(a1.w, 0.f));
#pragma unroll
    for (int et = 0; et < 4; ++et) {
      const short8v bf = *(const short8v*)&wfT[(size_t)(e0 + et * 16 + lo) * DQ + k];
      acc[et] = MFMA16(af.v, bf, acc[et]);
    }
  }
#pragma unroll
  for (int et = 0; et < 4; ++et)
#pragma unroll
    for (int r = 0; r < 4; ++r)
      qt[(size_t)(r0 + hi * 4 + r) * DK + e0 + et * 16 + lo] = f2bf(acc[et][r]);
}

// ---------------------------------------------------------------------------
// K3: fused MFMA attention, NA=4 tiles pipelined per block. 512 thr = 8 waves.
// Per tile: {reg->LDS stage + exact-f32 bias} | bar | {prefetch next keys->reg}
// QK | softmax | bar | P write | bar | PV + store | bar.
// Keys for tile i+1 load into VGPRs during tile i's compute (T14 split) so
// HBM latency hides under QK/softmax/PV.
// LDS: relu_lds 32K (swz (m&7)<<4), kT_lds 32K (swz ((d&7)^((d>>3)&7))<<4),
// P_lds 16K (swz ((q&7)^((q>>3)&7))<<4; bias[64] f32 aliases rows 0-1).
// Total exactly 80 KiB -> 2 blocks/CU; __launch_bounds__(512,4) caps VGPR 128.
// ---------------------------------------------------------------------------
__global__ __launch_bounds__(512, 4) void k_attn(
    const float* __restrict__ keys, const ushort* __restrict__ qt,
    const float* __restrict__ wm_w, const float* __restrict__ wm_b,
    const int* __restrict__ masks, float* __restrict__ out) {
  __shared__ ushort relu_lds[MM * DK];   // 32 KiB
  __shared__ ushort kT_lds[DK * MM];     // 32 KiB
  __shared__ ushort P_lds[EE * MM];      // 16 KiB
  float* biasf = (float*)P_lds;          // 64 f32, aliases P rows 0..1

  const int tid = threadIdx.x;
  const int w = tid >> 6;
  const int lane = tid & 63;
  const int lo = lane & 15, hi = lane >> 4;
  const int ba0 = blockIdx.x * NA;
  const int b = ba0 >> 7;

  // staging mapping: lane owns row srow, float4-chunks scol+8*it (it=0..7)
  const int srow = w * 8 + (lane >> 3);
  const int scol = lane & 7;
  const float4* wm4p = (const float4*)wm_w;
  const float wmb = wm_b[0];

  // qt A-fragments: wave w owns q rows 16w..16w+15, reused for all NA tiles
  const ushort* qrowp = qt + ((size_t)b * EE + w * 16 + lo) * DK + 8 * hi;
  short8v aq[8];
#pragma unroll
  for (int ks = 0; ks < 8; ++ks) aq[ks] = *(const short8v*)(qrowp + 32 * ks);

  // prologue: keys for tile 0 -> regs (8 float4 = full 128B lines per 8 lanes)
  float4 kreg[8];
  {
    const float4* kb4 = (const float4*)(keys + (size_t)ba0 * (MM * DK));
#pragma unroll
    for (int it = 0; it < 8; ++it) kreg[it] = kb4[srow * 64 + scol + 8 * it];
  }

  for (int i = 0; i < NA; ++i) {
    const int ba = ba0 + i;

    // ---- stage-write: kreg -> relu_lds + kT_lds, exact-f32 bias ----
    float bp = 0.f;
#pragma unroll
    for (int it = 0; it < 8; ++it) {
      const float4 v = kreg[it];
      const float4 wm4 = wm4p[scol + 8 * it];   // L1-hot after first tile
      const float rx = fmaxf(v.x, 0.f), ry = fmaxf(v.y, 0.f);
      const float rz = fmaxf(v.z, 0.f), rw = fmaxf(v.w, 0.f);
      bp += rx * wm4.x + ry * wm4.y + rz * wm4.z + rw * wm4.w;
      uint2 rr;
      rr.x = pack2(rx, ry); rr.y = pack2(rz, rw);
      *(uint2*)((char*)relu_lds + srow * 512 +
                (((scol + 8 * it) * 8) ^ ((srow & 7) << 4))) = rr;
      const float vj[4] = {v.x, v.y, v.z, v.w};
#pragma unroll
      for (int j = 0; j < 4; ++j) {
        const int d = (scol + 8 * it) * 4 + j;
        const int sw = ((d & 7) ^ ((d >> 3) & 7)) << 4;
        *(ushort*)((char*)kT_lds + d * 128 + ((2 * srow) ^ sw)) = f2bf(vj[j]);
      }
    }
    bp += __shfl_xor(bp, 1);
    bp += __shfl_xor(bp, 2);
    bp += __shfl_xor(bp, 4);
    if ((lane & 7) == 0) {
      const int mk = masks[(size_t)ba * MM + srow];
      biasf[srow] = mk ? (bp + wmb) : -1e12f;
    }
    __syncthreads();  // staging visible to all

    // ---- prefetch next tile's keys into regs (latency hides under compute) -
    if (i + 1 < NA) {
      const float4* kb4n = (const float4*)(keys + (size_t)(ba + 1) * (MM * DK));
#pragma unroll
      for (int it = 0; it < 8; ++it) kreg[it] = kb4n[srow * 64 + scol + 8 * it];
    }

    // ---- QK^T: wave = 16 q x 64 m, K=256 ----
    f32x4 sacc[4] = {f32x4{0.f, 0.f, 0.f, 0.f}, f32x4{0.f, 0.f, 0.f, 0.f},
                     f32x4{0.f, 0.f, 0.f, 0.f}, f32x4{0.f, 0.f, 0.f, 0.f}};
#pragma unroll
    for (int ks = 0; ks < 8; ++ks) {
#pragma unroll
      for (int mt = 0; mt < 4; ++mt) {
        const int m = mt * 16 + lo;
        const int k = ks * 32 + 8 * hi;
        const short8v bf = *(const short8v*)((char*)relu_lds + m * 512 +
                                             ((2 * k) ^ ((m & 7) << 4)));
        sacc[mt] = MFMA16(aq[ks], bf, sacc[mt]);
      }
    }

    // ---- softmax (rows q = 16w + 4*hi + r) ----
    const float scale = 0.036084391824351615f;  // 1/sqrt(768)
    float bias_v[4];
#pragma unroll
    for (int mt = 0; mt < 4; ++mt) bias_v[mt] = biasf[mt * 16 + lo];
    float ex[4][4], rmax[4], rsum[4];
#pragma unroll
    for (int r = 0; r < 4; ++r) rmax[r] = -3.4e38f;
#pragma unroll
    for (int mt = 0; mt < 4; ++mt)
#pragma unroll
      for (int r = 0; r < 4; ++r) {
        const float l = fmaf(sacc[mt][r], scale, bias_v[mt]);
        ex[mt][r] = l;
        rmax[r] = fmaxf(rmax[r], l);
      }
#pragma unroll
    for (int r = 0; r < 4; ++r) {
      rmax[r] = fmaxf(rmax[r], __shfl_xor(rmax[r], 1));
      rmax[r] = fmaxf(rmax[r], __shfl_xor(rmax[r], 2));
      rmax[r] = fmaxf(rmax[r], __shfl_xor(rmax[r], 4));
      rmax[r] = fmaxf(rmax[r], __shfl_xor(rmax[r], 8));
      rsum[r] = 0.f;
    }
#pragma unroll
    for (int mt = 0; mt < 4; ++mt)
#pragma unroll
      for (int r = 0; r < 4; ++r) {
        ex[mt][r] = __expf(ex[mt][r] - rmax[r]);
        rsum[r] += ex[mt][r];
      }
    float rinv[4];
#pragma unroll
    for (int r = 0; r < 4; ++r) {
      rsum[r] += __shfl_xor(rsum[r], 1);
      rsum[r] += __shfl_xor(rsum[r], 2);
      rsum[r] += __shfl_xor(rsum[r], 4);
      rsum[r] += __shfl_xor(rsum[r], 8);
      rinv[r] = 1.f / rsum[r];
    }

    __syncthreads();  // all bias reads done; P region may be overwritten

#pragma unroll
    for (int mt = 0; mt < 4; ++mt)
#pragma unroll
      for (int r = 0; r < 4; ++r) {
        const int q = w * 16 + hi * 4 + r;
        const int m = mt * 16 + lo;
        const int sw = ((q & 7) ^ ((q >> 3) & 7)) << 4;
        *(ushort*)((char*)P_lds + q * 128 + ((2 * m) ^ sw)) =
            f2bf(ex[mt][r] * rinv[r]);
      }
    __syncthreads();  // P complete

    // ---- PV (swapped): D[d][q], wave = 64 q x 64 d, K = 64 ----
    const int qb = 64 * (w >> 2);
    const int db = 64 * (w & 3);
    short8v ap[4][2];
#pragma unroll
    for (int qt_ = 0; qt_ < 4; ++qt_)
#pragma unroll
      for (int ks = 0; ks < 2; ++ks) {
        const int q = qb + qt_ * 16 + lo;
        const int m = ks * 32 + 8 * hi;
        const int sw = ((q & 7) ^ ((q >> 3) & 7)) << 4;
        ap[qt_][ks] = *(const short8v*)((char*)P_lds + q * 128 + ((2 * m) ^ sw));
      }
    float* ob = out + ((size_t)ba * EE) * DK;
#pragma unroll
    for (int dt = 0; dt < 4; ++dt) {
      short8v bk[2];
#pragma unroll
      for (int ks = 0; ks < 2; ++ks) {
        const int d = db + dt * 16 + lo;
        const int m = ks * 32 + 8 * hi;
        const int sw = ((d & 7) ^ ((d >> 3) & 7)) << 4;
        bk[ks] = *(const short8v*)((char*)kT_lds + d * 128 + ((2 * m) ^ sw));
      }
#pragma unroll
      for (int qt_ = 0; qt_ < 4; ++qt_) {
        f32x4 o = {0.f, 0.f, 0.f, 0.f};
        o = MFMA16(bk[0], ap[qt_][0], o);   // A = kT (rows=d), B = P (cols=q)
        o = MFMA16(bk[1], ap[qt_][1], o);
        const int q = qb + qt_ * 16 + lo;
        const int d = db + dt * 16 + (hi << 2);
        float4 ov;
        ov.x = o[0]; ov.y = o[1]; ov.z = o[2]; ov.w = o[3];
        *(float4*)&ob[(size_t)q * DK + d] = ov;   // 4 consecutive d, one q
      }
    }
    __syncthreads();  // PV reads done; next tile may overwrite LDS
  }
}

// ---------------------------------------------------------------------------
extern "C" void kernel_launch(void* const* d_in, const int* in_sizes, int n_in,
                              void* d_out, int out_size, void* d_ws, size_t ws_size,
                              hipStream_t stream) {
  const float* querys = (const float*)d_in[0];  // [16,128,768]
  const float* keys   = (const float*)d_in[1];  // [16,128,64,256]
  const float* Wq     = (const float*)d_in[2];  // [768,256]
  const float* Wk     = (const float*)d_in[3];  // [256,256]
  const float* Wm_w   = (const float*)d_in[4];  // [256]
  const float* Wm_b   = (const float*)d_in[5];  // [1]
  const int*   masks  = (const int*)d_in[6];    // [16,128,64]
  float* out = (float*)d_out;                   // [16,128,128,256]

  ushort* wfT   = (ushort*)d_ws;                          // 256*768 bf16
  ushort* qt_bf = (ushort*)((char*)d_ws + DK * DQ * 2);   // 2048*256 bf16

  k_wfuse<<<dim3(DK / 16, DQ / 64), 64, 0, stream>>>(Wq, Wk, wfT);
  k_qt<<<dim3((BB * EE) / 32, DK / 64), 128, 0, stream>>>(querys, wfT, qt_bf);
  k_attn<<<(BB * EE) / NA, 512, 0, stream>>>(keys, qt_bf, Wm_w, Wm_b, masks, out);
}

// Round 5
// 157.002 us; speedup vs baseline: 2.2657x; 2.2657x over previous
//
#include <hip/hip_runtime.h>
#include <hip/hip_bf16.h>

#define BB 16
#define EE 128
#define MM 64
#define DQ 768
#define DK 256

typedef __attribute__((ext_vector_type(8))) short short8v;   // 8 bf16 = 4 VGPR
typedef __attribute__((ext_vector_type(4))) float f32x4;

#define MFMA16(a, b, c) __builtin_amdgcn_mfma_f32_16x16x32_bf16(a, b, c, 0, 0, 0)

__device__ __forceinline__ ushort f2bf(float f) {
  __hip_bfloat16 h = __float2bfloat16(f);
  return *reinterpret_cast<ushort*>(&h);
}
__device__ __forceinline__ uint pack2(float lo, float hi) {
  return (uint)f2bf(lo) | ((uint)f2bf(hi) << 16);
}

// ---------------------------------------------------------------------------
// K1: WfT[e][d] = sum_k Wq[d][k] * Wk[e][k]  (= (Wq @ Wk^T)^T, bf16) via MFMA.
// ---------------------------------------------------------------------------
__global__ __launch_bounds__(64) void k_wfuse(const float* __restrict__ Wq,
                                              const float* __restrict__ Wk,
                                              ushort* __restrict__ wfT) {
  const int lane = threadIdx.x & 63;
  const int lo = lane & 15, hi = lane >> 4;
  const int e0 = blockIdx.x * 16;
  const int d0 = blockIdx.y * 64;
  f32x4 acc[4] = {f32x4{0.f, 0.f, 0.f, 0.f}, f32x4{0.f, 0.f, 0.f, 0.f},
                  f32x4{0.f, 0.f, 0.f, 0.f}, f32x4{0.f, 0.f, 0.f, 0.f}};
#pragma unroll
  for (int ks = 0; ks < 8; ++ks) {
    const int k = ks * 32 + 8 * hi;
    const float4 a0 = *(const float4*)&Wk[(size_t)(e0 + lo) * DK + k];
    const float4 a1 = *(const float4*)&Wk[(size_t)(e0 + lo) * DK + k + 4];
    union { short8v v; uint u[4]; } av;
    av.u[0] = pack2(a0.x, a0.y); av.u[1] = pack2(a0.z, a0.w);
    av.u[2] = pack2(a1.x, a1.y); av.u[3] = pack2(a1.z, a1.w);
#pragma unroll
    for (int dt = 0; dt < 4; ++dt) {
      const float4 b0 = *(const float4*)&Wq[(size_t)(d0 + dt * 16 + lo) * DK + k];
      const float4 b1 = *(const float4*)&Wq[(size_t)(d0 + dt * 16 + lo) * DK + k + 4];
      union { short8v v; uint u[4]; } bv;
      bv.u[0] = pack2(b0.x, b0.y); bv.u[1] = pack2(b0.z, b0.w);
      bv.u[2] = pack2(b1.x, b1.y); bv.u[3] = pack2(b1.z, b1.w);
      acc[dt] = MFMA16(av.v, bv.v, acc[dt]);
    }
  }
#pragma unroll
  for (int dt = 0; dt < 4; ++dt)
#pragma unroll
    for (int r = 0; r < 4; ++r)
      wfT[(size_t)(e0 + 4 * hi + r) * DQ + d0 + dt * 16 + lo] = f2bf(acc[dt][r]);
}

// ---------------------------------------------------------------------------
// K2: qt[r][e] = sum_d relu(querys[r][d]) * WfT[e][d], bf16 MFMA, no LDS.
// ---------------------------------------------------------------------------
__global__ __launch_bounds__(128) void k_qt(const float* __restrict__ querys,
                                            const ushort* __restrict__ wfT,
                                            ushort* __restrict__ qt) {
  const int tid = threadIdx.x;
  const int w = tid >> 6;
  const int lane = tid & 63;
  const int lo = lane & 15, hi = lane >> 4;
  const int r0 = blockIdx.x * 32 + w * 16;
  const int e0 = blockIdx.y * 64;
  const float* qrow = querys + (size_t)(r0 + lo) * DQ;
  f32x4 acc[4] = {f32x4{0.f, 0.f, 0.f, 0.f}, f32x4{0.f, 0.f, 0.f, 0.f},
                  f32x4{0.f, 0.f, 0.f, 0.f}, f32x4{0.f, 0.f, 0.f, 0.f}};
#pragma unroll
  for (int kc = 0; kc < DQ; kc += 32) {
    const int k = kc + 8 * hi;
    const float4 a0 = *(const float4*)&qrow[k];
    const float4 a1 = *(const float4*)&qrow[k + 4];
    union { short8v v; uint u[4]; } af;
    af.u[0] = pack2(fmaxf(a0.x, 0.f), fmaxf(a0.y, 0.f));
    af.u[1] = pack2(fmaxf(a0.z, 0.f), fmaxf(a0.w, 0.f));
    af.u[2] = pack2(fmaxf(a1.x, 0.f), fmaxf(a1.y, 0.f));
    af.u[3] = pack2(fmaxf(a1.z, 0.f), fmaxf(a1.w, 0.f));
#pragma unroll
    for (int et = 0; et < 4; ++et) {
      const short8v bf = *(const short8v*)&wfT[(size_t)(e0 + et * 16 + lo) * DQ + k];
      acc[et] = MFMA16(af.v, bf, acc[et]);
    }
  }
#pragma unroll
  for (int et = 0; et < 4; ++et)
#pragma unroll
    for (int r = 0; r < 4; ++r)
      qt[(size_t)(r0 + hi * 4 + r) * DK + e0 + et * 16 + lo] = f2bf(acc[et][r]);
}

// ---------------------------------------------------------------------------
// K3: fused MFMA attention, ONE barrier per block. 512 thr = 8 waves, one
// (b,a) per block, grid 2048.
//   stage keys->LDS | bar | per-wave: QK^T(swapped) -> in-lane softmax ->
//   P redistributed in-register (16 bpermute) -> PV (wave owns 16q x 256d)
// LDS: relu_lds [64 m][256 d] bf16 (swz (m&7)<<4)
//      kT_lds   [256 d][64 m] bf16 (swz ((d&7)^((d>>3)&7))<<4)
//      biasf[64] f32.  Total 65.8 KiB -> 2 blocks/CU.
// Swapped QK: sacc = mfma(A=relu_k rows m, B=qt cols q) = S^T[m][q]; lane
// owns column q = w*16+lo, m = mt*16+hi*4+r -> softmax is in-lane + 2 shfl.
// ---------------------------------------------------------------------------
__global__ __launch_bounds__(512, 4) void k_attn(
    const float* __restrict__ keys, const ushort* __restrict__ qt,
    const float* __restrict__ wm_w, const float* __restrict__ wm_b,
    const int* __restrict__ masks, float* __restrict__ out) {
  __shared__ ushort relu_lds[MM * DK];   // 32 KiB
  __shared__ ushort kT_lds[DK * MM];     // 32 KiB
  __shared__ float biasf[MM];            // 256 B

  const int tid = threadIdx.x;
  const int w = tid >> 6;
  const int lane = tid & 63;
  const int lo = lane & 15, hi = lane >> 4;
  const int ba = blockIdx.x;             // b*EE + a
  const int b = ba >> 7;

  // qt B-fragments (cols q = w*16+lo), issued early; L2-resident.
  const ushort* qrowp = qt + ((size_t)b * EE + w * 16 + lo) * DK + 8 * hi;
  short8v aq[8];
#pragma unroll
  for (int ks = 0; ks < 8; ++ks) aq[ks] = *(const short8v*)(qrowp + 32 * ks);

  // ================= stage: keys -> relu_lds + kT_lds + biasf ==============
  // wave w stages rows w*8..w*8+7 as 4 pairs; 16-lane group g owns pair
  // (m0, m0+1), lane cl covers float4-chunks cl+16*it.
  {
    const int g = hi, cl = lo;
    const int m0 = w * 8 + g * 2;
    const float4* kb4 = (const float4*)(keys + (size_t)ba * (MM * DK));
    const float4* wm4p = (const float4*)wm_w;
    float bp0 = 0.f, bp1 = 0.f;
#pragma unroll
    for (int it = 0; it < 4; ++it) {
      const int c = cl + 16 * it;                 // float4 chunk 0..63
      const float4 va = kb4[(size_t)m0 * 64 + c];
      const float4 vb = kb4[(size_t)(m0 + 1) * 64 + c];
      const float4 wm4 = wm4p[c];
      const float rx0 = fmaxf(va.x, 0.f), ry0 = fmaxf(va.y, 0.f);
      const float rz0 = fmaxf(va.z, 0.f), rw0 = fmaxf(va.w, 0.f);
      const float rx1 = fmaxf(vb.x, 0.f), ry1 = fmaxf(vb.y, 0.f);
      const float rz1 = fmaxf(vb.z, 0.f), rw1 = fmaxf(vb.w, 0.f);
      bp0 += rx0 * wm4.x + ry0 * wm4.y + rz0 * wm4.z + rw0 * wm4.w;
      bp1 += rx1 * wm4.x + ry1 * wm4.y + rz1 * wm4.z + rw1 * wm4.w;
      uint2 ra, rb;
      ra.x = pack2(rx0, ry0); ra.y = pack2(rz0, rw0);
      rb.x = pack2(rx1, ry1); rb.y = pack2(rz1, rw1);
      *(uint2*)((char*)relu_lds + (size_t)m0 * 512 +
                ((8 * c) ^ ((m0 & 7) << 4))) = ra;
      *(uint2*)((char*)relu_lds + (size_t)(m0 + 1) * 512 +
                ((8 * c) ^ (((m0 + 1) & 7) << 4))) = rb;
      const float va4[4] = {va.x, va.y, va.z, va.w};
      const float vb4[4] = {vb.x, vb.y, vb.z, vb.w};
#pragma unroll
      for (int j = 0; j < 4; ++j) {
        const int d = 4 * c + j;
        const int sw = ((d & 7) ^ ((d >> 3) & 7)) << 4;
        *(uint*)((char*)kT_lds + (size_t)d * 128 + ((2 * m0) ^ sw)) =
            pack2(va4[j], vb4[j]);
      }
    }
    bp0 += __shfl_xor(bp0, 1); bp1 += __shfl_xor(bp1, 1);
    bp0 += __shfl_xor(bp0, 2); bp1 += __shfl_xor(bp1, 2);
    bp0 += __shfl_xor(bp0, 4); bp1 += __shfl_xor(bp1, 4);
    bp0 += __shfl_xor(bp0, 8); bp1 += __shfl_xor(bp1, 8);
    if (cl == 0) {
      const float wmb = wm_b[0];
      const int mk0 = masks[(size_t)ba * MM + m0];
      const int mk1 = masks[(size_t)ba * MM + m0 + 1];
      biasf[m0] = mk0 ? (bp0 + wmb) : -1e12f;
      biasf[m0 + 1] = mk1 ? (bp1 + wmb) : -1e12f;
    }
  }
  __syncthreads();  // ONLY barrier: LDS fully staged; no LDS writes after.

  // ================= QK^T swapped: S^T[m][q], wave q = w*16+lo =============
  f32x4 sacc[4] = {f32x4{0.f, 0.f, 0.f, 0.f}, f32x4{0.f, 0.f, 0.f, 0.f},
                   f32x4{0.f, 0.f, 0.f, 0.f}, f32x4{0.f, 0.f, 0.f, 0.f}};
  __builtin_amdgcn_s_setprio(1);
#pragma unroll
  for (int ks = 0; ks < 8; ++ks) {
#pragma unroll
    for (int mt = 0; mt < 4; ++mt) {
      const int m = mt * 16 + lo;
      const int k = ks * 32 + 8 * hi;
      const short8v bf = *(const short8v*)((char*)relu_lds + (size_t)m * 512 +
                                           ((2 * k) ^ ((m & 7) << 4)));
      sacc[mt] = MFMA16(bf, aq[ks], sacc[mt]);  // A = relu_k (rows m), B = qt
    }
  }
  __builtin_amdgcn_s_setprio(0);

  // ================= softmax: in-lane over 16 m + shfl_xor 16,32 ===========
  const float scale = 0.036084391824351615f;  // 1/sqrt(768)
  float l[4][4];
  float mx = -3.4e38f;
#pragma unroll
  for (int mt = 0; mt < 4; ++mt) {
    const float4 bv = *(const float4*)&biasf[mt * 16 + hi * 4];
    const float bv4[4] = {bv.x, bv.y, bv.z, bv.w};
#pragma unroll
    for (int r = 0; r < 4; ++r) {
      l[mt][r] = fmaf(sacc[mt][r], scale, bv4[r]);
      mx = fmaxf(mx, l[mt][r]);
    }
  }
  mx = fmaxf(mx, __shfl_xor(mx, 16));
  mx = fmaxf(mx, __shfl_xor(mx, 32));
  float s = 0.f;
#pragma unroll
  for (int mt = 0; mt < 4; ++mt)
#pragma unroll
    for (int r = 0; r < 4; ++r) {
      l[mt][r] = __expf(l[mt][r] - mx);
      s += l[mt][r];
    }
  s += __shfl_xor(s, 16);
  s += __shfl_xor(s, 32);
  const float rinv = 1.f / s;

  // pack P column (q = w*16+lo) to bf16 pairs
  uint pk0[4], pk1[4];
#pragma unroll
  for (int mt = 0; mt < 4; ++mt) {
    pk0[mt] = pack2(l[mt][0] * rinv, l[mt][1] * rinv);
    pk1[mt] = pack2(l[mt][2] * rinv, l[mt][3] * rinv);
  }

  // ======== redistribute P into PV B-fragment layout (16 bpermutes) ========
  // target lane (lo,hi) frag[ks] holds P[m][q=lo'... q=w*16+lo], m = ks*32 +
  // 8*hi + 0..7; sources are lanes (lo, 2*(hi&1)) and (lo, 2*(hi&1)+1),
  // tile mt_src = 2*ks + (hi>>1).
  const int srcA = lo + 32 * (lane & 16 ? 1 : 0);  // lo + 32*(hi&1)
  const int srcB = srcA + 16;
  uint sa0[4], sa1[4], sb0[4], sb1[4];
#pragma unroll
  for (int mt = 0; mt < 4; ++mt) {
    sa0[mt] = (uint)__shfl((int)pk0[mt], srcA);
    sa1[mt] = (uint)__shfl((int)pk1[mt], srcA);
    sb0[mt] = (uint)__shfl((int)pk0[mt], srcB);
    sb1[mt] = (uint)__shfl((int)pk1[mt], srcB);
  }
  const bool ms = (hi >> 1) & 1;
  union { short8v v; uint u[4]; } pf0, pf1;
  pf0.u[0] = ms ? sa0[1] : sa0[0];
  pf0.u[1] = ms ? sa1[1] : sa1[0];
  pf0.u[2] = ms ? sb0[1] : sb0[0];
  pf0.u[3] = ms ? sb1[1] : sb1[0];
  pf1.u[0] = ms ? sa0[3] : sa0[2];
  pf1.u[1] = ms ? sa1[3] : sa1[2];
  pf1.u[2] = ms ? sb0[3] : sb0[2];
  pf1.u[3] = ms ? sb1[3] : sb1[2];

  // ================= PV: wave owns q = w*16..w*16+15, all 256 d ============
  float* ob = out + ((size_t)ba * EE + w * 16 + lo) * DK;  // this lane's q row
  __builtin_amdgcn_s_setprio(1);
#pragma unroll
  for (int dt = 0; dt < 16; ++dt) {
    const int d = dt * 16 + lo;
    const int sw = ((d & 7) ^ ((d >> 3) & 7)) << 4;
    const short8v bk0 = *(const short8v*)((char*)kT_lds + (size_t)d * 128 +
                                          ((16 * hi) ^ sw));
    const short8v bk1 = *(const short8v*)((char*)kT_lds + (size_t)d * 128 +
                                          ((64 + 16 * hi) ^ sw));
    f32x4 o = {0.f, 0.f, 0.f, 0.f};
    o = MFMA16(bk0, pf0.v, o);   // A = kT (rows d, k=m), B = P (cols q)
    o = MFMA16(bk1, pf1.v, o);
    float4 ov;
    ov.x = o[0]; ov.y = o[1]; ov.z = o[2]; ov.w = o[3];
    *(float4*)&ob[dt * 16 + hi * 4] = ov;   // 4 consecutive d, one q
  }
  __builtin_amdgcn_s_setprio(0);
}

// ---------------------------------------------------------------------------
extern "C" void kernel_launch(void* const* d_in, const int* in_sizes, int n_in,
                              void* d_out, int out_size, void* d_ws, size_t ws_size,
                              hipStream_t stream) {
  const float* querys = (const float*)d_in[0];  // [16,128,768]
  const float* keys   = (const float*)d_in[1];  // [16,128,64,256]
  const float* Wq     = (const float*)d_in[2];  // [768,256]
  const float* Wk     = (const float*)d_in[3];  // [256,256]
  const float* Wm_w   = (const float*)d_in[4];  // [256]
  const float* Wm_b   = (const float*)d_in[5];  // [1]
  const int*   masks  = (const int*)d_in[6];    // [16,128,64]
  float* out = (float*)d_out;                   // [16,128,128,256]

  ushort* wfT   = (ushort*)d_ws;                          // 256*768 bf16
  ushort* qt_bf = (ushort*)((char*)d_ws + DK * DQ * 2);   // 2048*256 bf16

  k_wfuse<<<dim3(DK / 16, DQ / 64), 64, 0, stream>>>(Wq, Wk, wfT);
  k_qt<<<dim3((BB * EE) / 32, DK / 64), 128, 0, stream>>>(querys, wfT, qt_bf);
  k_attn<<<BB * EE, 512, 0, stream>>>(keys, qt_bf, Wm_w, Wm_b, masks, out);
}

// Round 6
// 150.892 us; speedup vs baseline: 2.3575x; 1.0405x over previous
//
#include <hip/hip_runtime.h>
#include <hip/hip_bf16.h>

#define BB 16
#define EE 128
#define MM 64
#define DQ 768
#define DK 256
#define NT 8   // consecutive a-tiles per block (same b), double-buffered

typedef __attribute__((ext_vector_type(8))) short short8v;   // 8 bf16 = 4 VGPR
typedef __attribute__((ext_vector_type(4))) float f32x4;

#define MFMA16(a, b, c) __builtin_amdgcn_mfma_f32_16x16x32_bf16(a, b, c, 0, 0, 0)

// raw barrier: LDS visibility only; leaves global loads/stores in flight
#define LDS_BARRIER() asm volatile("s_waitcnt lgkmcnt(0)\n\ts_barrier" ::: "memory")

__device__ __forceinline__ ushort f2bf(float f) {
  __hip_bfloat16 h = __float2bfloat16(f);
  return *reinterpret_cast<ushort*>(&h);
}
__device__ __forceinline__ uint pack2(float lo, float hi) {
  return (uint)f2bf(lo) | ((uint)f2bf(hi) << 16);
}

// ---------------------------------------------------------------------------
// K1: WfT[e][d] = sum_k Wq[d][k] * Wk[e][k]  (= (Wq @ Wk^T)^T, bf16) via MFMA.
// ---------------------------------------------------------------------------
__global__ __launch_bounds__(64) void k_wfuse(const float* __restrict__ Wq,
                                              const float* __restrict__ Wk,
                                              ushort* __restrict__ wfT) {
  const int lane = threadIdx.x & 63;
  const int lo = lane & 15, hi = lane >> 4;
  const int e0 = blockIdx.x * 16;
  const int d0 = blockIdx.y * 64;
  f32x4 acc[4] = {f32x4{0.f, 0.f, 0.f, 0.f}, f32x4{0.f, 0.f, 0.f, 0.f},
                  f32x4{0.f, 0.f, 0.f, 0.f}, f32x4{0.f, 0.f, 0.f, 0.f}};
#pragma unroll
  for (int ks = 0; ks < 8; ++ks) {
    const int k = ks * 32 + 8 * hi;
    const float4 a0 = *(const float4*)&Wk[(size_t)(e0 + lo) * DK + k];
    const float4 a1 = *(const float4*)&Wk[(size_t)(e0 + lo) * DK + k + 4];
    union { short8v v; uint u[4]; } av;
    av.u[0] = pack2(a0.x, a0.y); av.u[1] = pack2(a0.z, a0.w);
    av.u[2] = pack2(a1.x, a1.y); av.u[3] = pack2(a1.z, a1.w);
#pragma unroll
    for (int dt = 0; dt < 4; ++dt) {
      const float4 b0 = *(const float4*)&Wq[(size_t)(d0 + dt * 16 + lo) * DK + k];
      const float4 b1 = *(const float4*)&Wq[(size_t)(d0 + dt * 16 + lo) * DK + k + 4];
      union { short8v v; uint u[4]; } bv;
      bv.u[0] = pack2(b0.x, b0.y); bv.u[1] = pack2(b0.z, b0.w);
      bv.u[2] = pack2(b1.x, b1.y); bv.u[3] = pack2(b1.z, b1.w);
      acc[dt] = MFMA16(av.v, bv.v, acc[dt]);
    }
  }
#pragma unroll
  for (int dt = 0; dt < 4; ++dt)
#pragma unroll
    for (int r = 0; r < 4; ++r)
      wfT[(size_t)(e0 + 4 * hi + r) * DQ + d0 + dt * 16 + lo] = f2bf(acc[dt][r]);
}

// ---------------------------------------------------------------------------
// K2: qt[r][e] = sum_d relu(querys[r][d]) * WfT[e][d], bf16 MFMA, no LDS.
// ---------------------------------------------------------------------------
__global__ __launch_bounds__(128) void k_qt(const float* __restrict__ querys,
                                            const ushort* __restrict__ wfT,
                                            ushort* __restrict__ qt) {
  const int tid = threadIdx.x;
  const int w = tid >> 6;
  const int lane = tid & 63;
  const int lo = lane & 15, hi = lane >> 4;
  const int r0 = blockIdx.x * 32 + w * 16;
  const int e0 = blockIdx.y * 64;
  const float* qrow = querys + (size_t)(r0 + lo) * DQ;
  f32x4 acc[4] = {f32x4{0.f, 0.f, 0.f, 0.f}, f32x4{0.f, 0.f, 0.f, 0.f},
                  f32x4{0.f, 0.f, 0.f, 0.f}, f32x4{0.f, 0.f, 0.f, 0.f}};
#pragma unroll
  for (int kc = 0; kc < DQ; kc += 32) {
    const int k = kc + 8 * hi;
    const float4 a0 = *(const float4*)&qrow[k];
    const float4 a1 = *(const float4*)&qrow[k + 4];
    union { short8v v; uint u[4]; } af;
    af.u[0] = pack2(fmaxf(a0.x, 0.f), fmaxf(a0.y, 0.f));
    af.u[1] = pack2(fmaxf(a0.z, 0.f), fmaxf(a0.w, 0.f));
    af.u[2] = pack2(fmaxf(a1.x, 0.f), fmaxf(a1.y, 0.f));
    af.u[3] = pack2(fmaxf(a1.z, 0.f), fmaxf(a1.w, 0.f));
#pragma unroll
    for (int et = 0; et < 4; ++et) {
      const short8v bf = *(const short8v*)&wfT[(size_t)(e0 + et * 16 + lo) * DQ + k];
      acc[et] = MFMA16(af.v, bf, acc[et]);
    }
  }
#pragma unroll
  for (int et = 0; et < 4; ++et)
#pragma unroll
    for (int r = 0; r < 4; ++r)
      qt[(size_t)(r0 + hi * 4 + r) * DK + e0 + et * 16 + lo] = f2bf(acc[et][r]);
}

// ---------------------------------------------------------------------------
// K3: fused MFMA attention, NT=8 tiles per block, double-buffered LDS, one
// raw barrier per tile. 512 thr = 8 waves. Grid 256 (1 block/CU, 8 waves/CU).
// Tile t lives in buffer t&1. Per iteration i:
//   stage-write buf^1 (tile i+1, from kreg loaded at i-1)  [T14 write-late]
//   issue kreg loads tile i+2                              [T14 issue-early]
//   compute tile i: QK^T(swapped) -> in-lane softmax -> reg P redistribute
//                   -> PV (wave owns 16q x 256d) -> float4 stores
//   s_waitcnt lgkmcnt(0); s_barrier   (no vmcnt drain: loads/stores in flight)
// LDS: relu[2] 64K total (swz (m&7)<<4), kT[2] 64K (swz ((d&7)^((d>>3)&7))<<4),
// bias[2][64] f32 -> 131.5 KiB. __launch_bounds__(512,2) -> 256 VGPR cap, no
// spill (round-4 failure mode excluded).
// ---------------------------------------------------------------------------
__global__ __launch_bounds__(512, 2) void k_attn(
    const float* __restrict__ keys, const ushort* __restrict__ qt,
    const float* __restrict__ wm_w, const float* __restrict__ wm_b,
    const int* __restrict__ masks, float* __restrict__ out) {
  __shared__ ushort relu_lds[2][MM * DK];        // 2 x 32 KiB
  __shared__ ushort kT_lds[2][DK * MM];          // 2 x 32 KiB
  __shared__ __attribute__((aligned(16))) float biasf[2][MM];  // 2 x 256 B

  const int tid = threadIdx.x;
  const int w = tid >> 6;
  const int lane = tid & 63;
  const int lo = lane & 15, hi = lane >> 4;
  const int ba0 = blockIdx.x * NT;
  const int b = ba0 >> 7;                        // NT | 128 -> b fixed

  // staging mapping: 16-lane group hi of wave w owns row pair (m0, m0+1);
  // lane lo covers float4 chunks c = lo + 16*it.
  const int m0 = w * 8 + hi * 2;

  // wm fragments for this lane's chunks (fixed across tiles)
  const float4* wm4p = (const float4*)wm_w;
  float4 wmreg[4];
#pragma unroll
  for (int it = 0; it < 4; ++it) wmreg[it] = wm4p[lo + 16 * it];
  const float wmb = wm_b[0];

  // qt B-fragments (cols q = w*16+lo), loaded ONCE for all NT tiles
  const ushort* qrowp = qt + ((size_t)b * EE + w * 16 + lo) * DK + 8 * hi;
  short8v aq[8];
#pragma unroll
  for (int ks = 0; ks < 8; ++ks) aq[ks] = *(const short8v*)(qrowp + 32 * ks);

  float4 kreg[8];
  int mk0, mk1;
  auto load_kreg = [&](int t) {
    const float4* p = (const float4*)(keys + (size_t)(ba0 + t) * (MM * DK));
#pragma unroll
    for (int it = 0; it < 4; ++it) {
      kreg[2 * it]     = p[(size_t)m0 * 64 + lo + 16 * it];
      kreg[2 * it + 1] = p[(size_t)(m0 + 1) * 64 + lo + 16 * it];
    }
    mk0 = masks[(size_t)(ba0 + t) * MM + m0];
    mk1 = masks[(size_t)(ba0 + t) * MM + m0 + 1];
  };

  auto stage_write = [&](int nbuf) {
    float bp0 = 0.f, bp1 = 0.f;
#pragma unroll
    for (int it = 0; it < 4; ++it) {
      const int c = lo + 16 * it;
      const float4 va = kreg[2 * it], vb = kreg[2 * it + 1];
      const float4 wm4 = wmreg[it];
      const float rx0 = fmaxf(va.x, 0.f), ry0 = fmaxf(va.y, 0.f);
      const float rz0 = fmaxf(va.z, 0.f), rw0 = fmaxf(va.w, 0.f);
      const float rx1 = fmaxf(vb.x, 0.f), ry1 = fmaxf(vb.y, 0.f);
      const float rz1 = fmaxf(vb.z, 0.f), rw1 = fmaxf(vb.w, 0.f);
      bp0 += rx0 * wm4.x + ry0 * wm4.y + rz0 * wm4.z + rw0 * wm4.w;
      bp1 += rx1 * wm4.x + ry1 * wm4.y + rz1 * wm4.z + rw1 * wm4.w;
      uint2 ra, rb;
      ra.x = pack2(rx0, ry0); ra.y = pack2(rz0, rw0);
      rb.x = pack2(rx1, ry1); rb.y = pack2(rz1, rw1);
      *(uint2*)((char*)relu_lds[nbuf] + (size_t)m0 * 512 +
                ((8 * c) ^ ((m0 & 7) << 4))) = ra;
      *(uint2*)((char*)relu_lds[nbuf] + (size_t)(m0 + 1) * 512 +
                ((8 * c) ^ (((m0 + 1) & 7) << 4))) = rb;
      const float va4[4] = {va.x, va.y, va.z, va.w};
      const float vb4[4] = {vb.x, vb.y, vb.z, vb.w};
#pragma unroll
      for (int j = 0; j < 4; ++j) {
        const int d = 4 * c + j;
        const int sw = ((d & 7) ^ ((d >> 3) & 7)) << 4;
        *(uint*)((char*)kT_lds[nbuf] + (size_t)d * 128 + ((2 * m0) ^ sw)) =
            pack2(va4[j], vb4[j]);
      }
    }
    bp0 += __shfl_xor(bp0, 1); bp1 += __shfl_xor(bp1, 1);
    bp0 += __shfl_xor(bp0, 2); bp1 += __shfl_xor(bp1, 2);
    bp0 += __shfl_xor(bp0, 4); bp1 += __shfl_xor(bp1, 4);
    bp0 += __shfl_xor(bp0, 8); bp1 += __shfl_xor(bp1, 8);
    if (lo == 0) {
      biasf[nbuf][m0]     = mk0 ? (bp0 + wmb) : -1e12f;
      biasf[nbuf][m0 + 1] = mk1 ? (bp1 + wmb) : -1e12f;
    }
  };

  // ---- prologue: tile 0 staged, tile 1 in regs ----
  load_kreg(0);
  stage_write(0);
  load_kreg(1);
  LDS_BARRIER();

  for (int i = 0; i < NT; ++i) {
    const int buf = i & 1;
    if (i + 1 < NT) stage_write(buf ^ 1);   // tile i+1 -> other buffer
    if (i + 2 < NT) load_kreg(i + 2);       // fire-and-forget prefetch

    // ================= QK^T swapped: S^T[m][q], lane owns q = w*16+lo ======
    f32x4 sacc[4] = {f32x4{0.f, 0.f, 0.f, 0.f}, f32x4{0.f, 0.f, 0.f, 0.f},
                     f32x4{0.f, 0.f, 0.f, 0.f}, f32x4{0.f, 0.f, 0.f, 0.f}};
    __builtin_amdgcn_s_setprio(1);
#pragma unroll
    for (int ks = 0; ks < 8; ++ks) {
#pragma unroll
      for (int mt = 0; mt < 4; ++mt) {
        const int m = mt * 16 + lo;
        const int k = ks * 32 + 8 * hi;
        const short8v bf = *(const short8v*)((char*)relu_lds[buf] +
                                             (size_t)m * 512 +
                                             ((2 * k) ^ ((m & 7) << 4)));
        sacc[mt] = MFMA16(bf, aq[ks], sacc[mt]);  // A = relu_k, B = qt
      }
    }
    __builtin_amdgcn_s_setprio(0);

    // ================= softmax: in-lane over 16 m + shfl_xor 16,32 =========
    const float scale = 0.036084391824351615f;  // 1/sqrt(768)
    float l[4][4];
    float mx = -3.4e38f;
#pragma unroll
    for (int mt = 0; mt < 4; ++mt) {
      const float4 bv = *(const float4*)&biasf[buf][mt * 16 + hi * 4];
      const float bv4[4] = {bv.x, bv.y, bv.z, bv.w};
#pragma unroll
      for (int r = 0; r < 4; ++r) {
        l[mt][r] = fmaf(sacc[mt][r], scale, bv4[r]);
        mx = fmaxf(mx, l[mt][r]);
      }
    }
    mx = fmaxf(mx, __shfl_xor(mx, 16));
    mx = fmaxf(mx, __shfl_xor(mx, 32));
    float s = 0.f;
#pragma unroll
    for (int mt = 0; mt < 4; ++mt)
#pragma unroll
      for (int r = 0; r < 4; ++r) {
        l[mt][r] = __expf(l[mt][r] - mx);
        s += l[mt][r];
      }
    s += __shfl_xor(s, 16);
    s += __shfl_xor(s, 32);
    const float rinv = 1.f / s;

    uint pk0[4], pk1[4];
#pragma unroll
    for (int mt = 0; mt < 4; ++mt) {
      pk0[mt] = pack2(l[mt][0] * rinv, l[mt][1] * rinv);
      pk1[mt] = pack2(l[mt][2] * rinv, l[mt][3] * rinv);
    }

    // ======== redistribute P into PV B-fragment layout (16 bpermutes) ======
    const int srcA = lo + 32 * ((lane >> 4) & 1);
    const int srcB = srcA + 16;
    uint sa0[4], sa1[4], sb0[4], sb1[4];
#pragma unroll
    for (int mt = 0; mt < 4; ++mt) {
      sa0[mt] = (uint)__shfl((int)pk0[mt], srcA);
      sa1[mt] = (uint)__shfl((int)pk1[mt], srcA);
      sb0[mt] = (uint)__shfl((int)pk0[mt], srcB);
      sb1[mt] = (uint)__shfl((int)pk1[mt], srcB);
    }
    const bool ms = (hi >> 1) & 1;
    union { short8v v; uint u[4]; } pf0, pf1;
    pf0.u[0] = ms ? sa0[1] : sa0[0];
    pf0.u[1] = ms ? sa1[1] : sa1[0];
    pf0.u[2] = ms ? sb0[1] : sb0[0];
    pf0.u[3] = ms ? sb1[1] : sb1[0];
    pf1.u[0] = ms ? sa0[3] : sa0[2];
    pf1.u[1] = ms ? sa1[3] : sa1[2];
    pf1.u[2] = ms ? sb0[3] : sb0[2];
    pf1.u[3] = ms ? sb1[3] : sb1[2];

    // ================= PV: wave owns q = w*16..w*16+15, all 256 d ==========
    float* ob = out + ((size_t)(ba0 + i) * EE + w * 16 + lo) * DK;
    __builtin_amdgcn_s_setprio(1);
#pragma unroll
    for (int dt = 0; dt < 16; ++dt) {
      const int d = dt * 16 + lo;
      const int sw = ((d & 7) ^ ((d >> 3) & 7)) << 4;
      const short8v bk0 = *(const short8v*)((char*)kT_lds[buf] +
                                            (size_t)d * 128 + ((16 * hi) ^ sw));
      const short8v bk1 = *(const short8v*)((char*)kT_lds[buf] +
                                            (size_t)d * 128 +
                                            ((64 + 16 * hi) ^ sw));
      f32x4 o = {0.f, 0.f, 0.f, 0.f};
      o = MFMA16(bk0, pf0.v, o);   // A = kT (rows d, k=m), B = P (cols q)
      o = MFMA16(bk1, pf1.v, o);
      float4 ov;
      ov.x = o[0]; ov.y = o[1]; ov.z = o[2]; ov.w = o[3];
      *(float4*)&ob[dt * 16 + hi * 4] = ov;
    }
    __builtin_amdgcn_s_setprio(0);

    if (i + 1 < NT) LDS_BARRIER();
  }
}

// ---------------------------------------------------------------------------
extern "C" void kernel_launch(void* const* d_in, const int* in_sizes, int n_in,
                              void* d_out, int out_size, void* d_ws, size_t ws_size,
                              hipStream_t stream) {
  const float* querys = (const float*)d_in[0];  // [16,128,768]
  const float* keys   = (const float*)d_in[1];  // [16,128,64,256]
  const float* Wq     = (const float*)d_in[2];  // [768,256]
  const float* Wk     = (const float*)d_in[3];  // [256,256]
  const float* Wm_w   = (const float*)d_in[4];  // [256]
  const float* Wm_b   = (const float*)d_in[5];  // [1]
  const int*   masks  = (const int*)d_in[6];    // [16,128,64]
  float* out = (float*)d_out;                   // [16,128,128,256]

  ushort* wfT   = (ushort*)d_ws;                          // 256*768 bf16
  ushort* qt_bf = (ushort*)((char*)d_ws + DK * DQ * 2);   // 2048*256 bf16

  k_wfuse<<<dim3(DK / 16, DQ / 64), 64, 0, stream>>>(Wq, Wk, wfT);
  k_qt<<<dim3((BB * EE) / 32, DK / 64), 128, 0, stream>>>(querys, wfT, qt_bf);
  k_attn<<<(BB * EE) / NT, 512, 0, stream>>>(keys, qt_bf, Wm_w, Wm_b, masks, out);
}